// Round 11
// baseline (29.022 us; speedup 1.0000x reference)
//
#include <hip/hip_runtime.h>

// QuantHotLowRank: out[n][d] = sum_r Uq[ids[n]][r] * Bq[r][d]
// K=200000, R=64, D=1024, N=16384, 4-bit groupwise fake-quant, group=32.
//
// SINGLE kernel (no grid sync -- R9 measured cooperative sync at 5.7x worse;
// R10 measured the 2-kernel path's quantB+gap at ~5.5 us of pure structure):
// each block quantizes its own 128-col B-slice DIRECTLY into LDS from raw
// fp32 B (quant groups = 32 consecutive cols of one row -> thread-local amax,
// no shuffles; 32 fp64 divs/thread of redundant work hides under the memory
// phase), gathers + fp64-quantizes its A rows in-register, runs split-bf16
// MFMA (hi*hi + hi*lo + lo*hi, exact to ~2^-18), and stores via LDS
// transpose + coalesced nontemporal dwordx4.
//
// Tile map: mb = bx & 127, nb = bx >> 7. Blocks sharing U rows (same mb) are
// 128 apart == same XCD (128%8==0) -> gathered U rows hit that XCD's L2 on
// the 7 re-reads. Raw B is 256KB -> resident in every L2 regardless.
//
// Quant decisions in FP64 to bit-match the numpy-fp64 reference (fp32 flips
// levels at w/scale ~ n+.5 -> absmax 1.06; fp64 -> 0.25 = 1 bf16 ULP floor).

#define R_DIM 64
#define D_DIM 1024
#define N_IDS 16384

#define BM 128         // rows per tile (4 waves x 2 m-frags x 16)
#define BN 128         // cols per tile
#define LDS_STRIDE 72  // ushorts per B-LDS row: 64 + 8 pad (kills bank conflicts)
#define OT_STRIDE 132  // floats per out-LDS row: 128 + 4 pad

typedef __attribute__((ext_vector_type(8))) __bf16 bf16x8;
typedef __attribute__((ext_vector_type(4))) float f32x4;

__device__ inline unsigned short f32_to_bf16_rne(float f) {
  union { float f; unsigned int u; } c; c.f = f;
  unsigned int u = c.u;
  u += 0x7fffu + ((u >> 16) & 1u);   // round-to-nearest-even (finite inputs only)
  return (unsigned short)(u >> 16);
}

__device__ inline float bf16_bits_to_f32(unsigned short h) {
  union { unsigned int u; float f; } c; c.u = ((unsigned int)h) << 16;
  return c.f;
}

// fp64 fake-quant of one element given the group's fp64 scale (= amax/7,
// hoisted -- identical bits to recomputing per element).
__device__ inline void quant_elem(float w, double scale,
                                  unsigned short* hi, unsigned short* lo) {
  double t = (double)w / scale;                    // exact IEEE fp64 div = np
  double q = fmin(fmax(rint(t), -7.0), 7.0) * scale;
  float qf = (float)q;
  unsigned short h = f32_to_bf16_rne(qf);
  *hi = h;
  *lo = f32_to_bf16_rne(qf - bf16_bits_to_f32(h));
}

// ---------------- fused kernel: B-quant->LDS, A-quant->regs, MFMA, store ----
__global__ __launch_bounds__(256, 4) void gemm_kernel(
    const float* __restrict__ U, const float* __restrict__ B,
    const int* __restrict__ ids, float* __restrict__ out) {
  // B tiles (2 planes, 18KB each); reused as the fp32 out-transpose buffer
  // (33KB) in the store phase. 36864B -> 4 blocks/CU.
  __shared__ char smem[2 * BN * LDS_STRIDE * 2];
  unsigned short* bt_hi = (unsigned short*)smem;
  unsigned short* bt_lo = bt_hi + BN * LDS_STRIDE;
  float* ot = (float*)smem;

  const int tid  = threadIdx.x;
  const int lane = tid & 63;
  const int wave = tid >> 6;
  const int bx   = blockIdx.x;
  const int mb   = bx & 127;   // same-U-rows blocks are 128 apart == same XCD
  const int nb   = bx >> 7;    // 8 col-slices
  const int n0   = nb * BN;
  const int m0b  = mb * BM;
  const int koff  = (lane >> 4) * 8;         // k-chunk of 8 within the 32-group
  const int nlane = lane & 15;

  // --- A gather loads FIRST (in flight under the B-quant VALU work) --------
  const float* urow0 = U + (size_t)ids[m0b + wave * 16 + nlane] * R_DIM;
  const float* urow1 = U + (size_t)ids[m0b + 64 + wave * 16 + nlane] * R_DIM;
  float4 wr[2][2][2];
  #pragma unroll
  for (int s = 0; s < 2; ++s) {
    wr[0][s][0] = *(const float4*)(urow0 + s * 32 + koff);
    wr[0][s][1] = *(const float4*)(urow0 + s * 32 + koff + 4);
    wr[1][s][0] = *(const float4*)(urow1 + s * 32 + koff);
    wr[1][s][1] = *(const float4*)(urow1 + s * 32 + koff + 4);
  }

  // --- quantize this block's B-slice straight into LDS ---------------------
  // Thread t -> row r = t>>2, quant-group g = t&3 (cols n0+g*32 .. +32 of
  // row r = exactly one group): amax is thread-local, fp64 ops bit-identical
  // to the two-kernel version (fmax is exact, order-free).
  {
    const int r = tid >> 2, g = tid & 3;
    const float* bp = B + (size_t)r * D_DIM + n0 + g * 32;
    float4 bv[8];
    #pragma unroll
    for (int q = 0; q < 8; ++q) bv[q] = *(const float4*)(bp + q * 4);
    float a = 0.0f;
    #pragma unroll
    for (int q = 0; q < 8; ++q)
      a = fmaxf(a, fmaxf(fmaxf(fabsf(bv[q].x), fabsf(bv[q].y)),
                         fmaxf(fabsf(bv[q].z), fabsf(bv[q].w))));
    double sc = fmax((double)a, 1e-8) / 7.0;
    #pragma unroll
    for (int q = 0; q < 8; ++q) {
      float wv[4] = {bv[q].x, bv[q].y, bv[q].z, bv[q].w};
      #pragma unroll
      for (int j = 0; j < 4; ++j) {
        unsigned short hi, lo;
        quant_elem(wv[j], sc, &hi, &lo);
        const int c = g * 32 + q * 4 + j;          // local col 0..127
        bt_hi[c * LDS_STRIDE + r] = hi;
        bt_lo[c * LDS_STRIDE + r] = lo;
      }
    }
  }

  // --- fp64-quantize A fragments in-register -------------------------------
  // Lane holds elems s*32+koff..+8 of its row; lanes {l&15 fixed, l>>4
  // varying} hold one 32-elem quant group -> amax via shfl_xor 16/32.
  bf16x8 ah[2][2], al[2][2];
  #pragma unroll
  for (int mf = 0; mf < 2; ++mf) {
    #pragma unroll
    for (int s = 0; s < 2; ++s) {
      float4 w0 = wr[mf][s][0], w1 = wr[mf][s][1];
      float wv[8] = {w0.x, w0.y, w0.z, w0.w, w1.x, w1.y, w1.z, w1.w};
      float a = 0.0f;
      #pragma unroll
      for (int j = 0; j < 8; ++j) a = fmaxf(a, fabsf(wv[j]));
      a = fmaxf(a, __shfl_xor(a, 16));
      a = fmaxf(a, __shfl_xor(a, 32));
      double sc = fmax((double)a, 1e-8) / 7.0;
      union { unsigned short s8[8]; bf16x8 b; } uh, ul;
      #pragma unroll
      for (int j = 0; j < 8; ++j) {
        unsigned short hi, lo;
        quant_elem(wv[j], sc, &hi, &lo);
        uh.s8[j] = hi;
        ul.s8[j] = lo;
      }
      ah[mf][s] = uh.b;
      al[mf][s] = ul.b;
    }
  }

  __syncthreads();   // B planes fully written

  // --- MFMA: 8 n-frags x 2 k-steps x 2 m-frags x {hi*hi, hi*lo, lo*hi} -----
  f32x4 acc[2][8];
  #pragma unroll
  for (int mf = 0; mf < 2; ++mf)
    #pragma unroll
    for (int nf = 0; nf < 8; ++nf) acc[mf][nf] = (f32x4){0.f, 0.f, 0.f, 0.f};

  #pragma unroll
  for (int nf = 0; nf < 8; ++nf) {
    #pragma unroll
    for (int s = 0; s < 2; ++s) {
      const int boff = (nf * 16 + nlane) * LDS_STRIDE + s * 32 + koff;
      union { uint4 u; bf16x8 b; } bh, bl;
      bh.u = *(const uint4*)&bt_hi[boff];
      bl.u = *(const uint4*)&bt_lo[boff];
      #pragma unroll
      for (int mf = 0; mf < 2; ++mf) {
        acc[mf][nf] = __builtin_amdgcn_mfma_f32_16x16x32_bf16(ah[mf][s], bh.b, acc[mf][nf], 0, 0, 0);
        acc[mf][nf] = __builtin_amdgcn_mfma_f32_16x16x32_bf16(ah[mf][s], bl.b, acc[mf][nf], 0, 0, 0);
        acc[mf][nf] = __builtin_amdgcn_mfma_f32_16x16x32_bf16(al[mf][s], bh.b, acc[mf][nf], 0, 0, 0);
      }
    }
  }

  __syncthreads();   // done reading B tiles; reuse smem for out-transpose

  // --- per-wave LDS transpose + coalesced nt stores, one round per m-frag ---
  float* wp = ot + wave * 16 * OT_STRIDE;
  #pragma unroll
  for (int mf = 0; mf < 2; ++mf) {
    const int r0 = (lane >> 4) << 2;         // 0,4,8,12
    #pragma unroll
    for (int nf = 0; nf < 8; ++nf) {
      #pragma unroll
      for (int i = 0; i < 4; ++i) {
        wp[(r0 + i) * OT_STRIDE + nlane + nf * 16] = acc[mf][nf][i];
      }
    }
    const int orow0 = m0b + mf * 64 + wave * 16;
    #pragma unroll
    for (int j = 0; j < 8; ++j) {
      const int row = j * 2 + (lane >> 5);   // 0..15
      f32x4 v = *(const f32x4*)&wp[row * OT_STRIDE + (lane & 31) * 4];
      // 32 lanes x 16B = one contiguous 512B row segment; nt write-once stream
      __builtin_nontemporal_store(v,
          (f32x4*)&out[(size_t)(orow0 + row) * D_DIM + n0 + (lane & 31) * 4]);
    }
  }
}

extern "C" void kernel_launch(void* const* d_in, const int* in_sizes, int n_in,
                              void* d_out, int out_size, void* d_ws, size_t ws_size,
                              hipStream_t stream) {
  const float* U   = (const float*)d_in[0];
  const float* B   = (const float*)d_in[1];
  const int*   ids = (const int*)d_in[2];
  float* out = (float*)d_out;

  gemm_kernel<<<(N_IDS / BM) * (D_DIM / BN), 256, 0, stream>>>(U, B, ids, out);
}